// Round 5
// baseline (1304.992 us; speedup 1.0000x reference)
//
#include <hip/hip_runtime.h>
#include <hip/hip_bf16.h>
#include <math.h>

typedef unsigned short u16;
typedef __bf16 bf16x8 __attribute__((ext_vector_type(8)));
typedef float f32x4 __attribute__((ext_vector_type(4)));

#define B_  2
#define S_  2048
#define D_  4096
#define H_  32
#define HD_ 128

__device__ __forceinline__ unsigned rne_bf16(float x) {
  unsigned u = __float_as_uint(x);
  return (u + 0x7fffu + ((u >> 16) & 1u)) >> 16;
}

__device__ __forceinline__ void async16(void* lds_p, const void* g) {
  __builtin_amdgcn_global_load_lds(
      (__attribute__((address_space(1))) void*)(g),
      (__attribute__((address_space(3))) void*)(lds_p), 16, 0, 0);
}

// ---------------------------------------------------------------- convert
__global__ __launch_bounds__(256) void convert_bf16(
    const float* __restrict__ src, u16* __restrict__ dst, int n8) {
  int i = blockIdx.x * 256 + threadIdx.x;
  if (i >= n8) return;
  const float4* s = (const float4*)src + (size_t)i * 2;
  float4 a = s[0], b = s[1];
  uint4 o;
  o.x = rne_bf16(a.x) | (rne_bf16(a.y) << 16);
  o.y = rne_bf16(a.z) | (rne_bf16(a.w) << 16);
  o.z = rne_bf16(b.x) | (rne_bf16(b.y) << 16);
  o.w = rne_bf16(b.z) | (rne_bf16(b.w) << 16);
  ((uint4*)dst)[i] = o;
}

// fused 4-tensor convert: saves 3 launch gaps
__global__ __launch_bounds__(256) void convert_bf16_x4(
    const float* __restrict__ s0, const float* __restrict__ s1,
    const float* __restrict__ s2, const float* __restrict__ s3,
    u16* __restrict__ d0, u16* __restrict__ d1,
    u16* __restrict__ d2, u16* __restrict__ d3) {
  const int per = (B_ * S_ * D_) / 8 / 256;  // blocks per tensor
  const int which = blockIdx.x / per;
  const int i = (blockIdx.x % per) * 256 + threadIdx.x;
  const float* src = which == 0 ? s0 : which == 1 ? s1 : which == 2 ? s2 : s3;
  u16* dst = which == 0 ? d0 : which == 1 ? d1 : which == 2 ? d2 : d3;
  const float4* s = (const float4*)src + (size_t)i * 2;
  float4 a = s[0], b = s[1];
  uint4 o;
  o.x = rne_bf16(a.x) | (rne_bf16(a.y) << 16);
  o.y = rne_bf16(a.z) | (rne_bf16(a.w) << 16);
  o.z = rne_bf16(b.x) | (rne_bf16(b.y) << 16);
  o.w = rne_bf16(b.z) | (rne_bf16(b.w) << 16);
  ((uint4*)dst)[i] = o;
}

// ---------------------------------------------------------------- GEMM
// EXACT R2-verified kernel (193 us, MfmaUtil 32%, FETCH 127MB): 128x128
// tile, BK=32, 4 waves, double-buffered LDS with issue-early prefetch and
// a single __syncthreads per K-step. R1/R3 (8-phase) and R4 (3-buffer
// counted-vmcnt) both regressed -> this structure is the session keeper.
template <int MODE>
__global__ __launch_bounds__(256, 3) void gemm_bt(
    const u16* __restrict__ A, const u16* __restrict__ Bw,
    u16* __restrict__ outB, float* __restrict__ outF,
    const float* __restrict__ fc, const float* __restrict__ fs) {
  // buf p at p*8192 (u16): A tile 128x32 at +0, B tile at +4096. 32 KB total.
  __shared__ __align__(16) u16 lds[16384];
  const int tid  = threadIdx.x;
  const int lane = tid & 63;
  const int wave = tid >> 6;
  const int lm   = lane & 15, quad = lane >> 4;
  const int mr = (wave >> 1) * 64, nc = (wave & 1) * 64;
  const int K = 4096;
  const int NT = K / 32;  // 128 K-steps

  // XCD-aware 2D-blocked swizzle: XCD x owns an 8-row x 16-col rectangle.
  const int bid = blockIdx.y * 32 + blockIdx.x;
  const int xg = bid & 7, l = bid >> 3;
  const int m0 = (((xg & 3) * 8) + (l & 7)) * 128;
  const int n0 = (((xg >> 2) * 16) + (l >> 3)) * 128;

  const int ca = tid, cb = tid + 256;
  const int ra = ca >> 2, ga = ((ca & 3) ^ ((ca >> 3) & 3)) * 8;
  const int rb = cb >> 2, gb = ((cb & 3) ^ ((cb >> 3) & 3)) * 8;
  const u16* Ag0 = A + (size_t)(m0 + ra) * K + ga;
  const u16* Ag1 = A + (size_t)(m0 + rb) * K + gb;
  const u16* Bg0 = Bw + (size_t)(n0 + ra) * K + ga;
  const u16* Bg1 = Bw + (size_t)(n0 + rb) * K + gb;

  const int koff = (quad ^ ((lm >> 1) & 3)) * 8;

  f32x4 acc[4][4] = {};

  // prologue: stage tile 0 into buf 0
  async16(&lds[ca * 8], Ag0);
  async16(&lds[cb * 8], Ag1);
  async16(&lds[4096 + ca * 8], Bg0);
  async16(&lds[4096 + cb * 8], Bg1);
  __syncthreads();

  for (int t = 0; t < NT; ++t) {
    const u16* As = lds + (t & 1) * 8192;
    const u16* Bs = As + 4096;
    if (t < NT - 1) {  // prefetch t+1 into the other buffer (issue-early)
      u16* Ld = lds + ((t + 1) & 1) * 8192;
      const size_t ko = (size_t)(t + 1) * 32;
      async16(&Ld[ca * 8], Ag0 + ko);
      async16(&Ld[cb * 8], Ag1 + ko);
      async16(&Ld[4096 + ca * 8], Bg0 + ko);
      async16(&Ld[4096 + cb * 8], Bg1 + ko);
    }
    bf16x8 af[4], bfr[4];
#pragma unroll
    for (int i = 0; i < 4; ++i) af[i] = *(const bf16x8*)&As[(mr + i * 16 + lm) * 32 + koff];
#pragma unroll
    for (int j = 0; j < 4; ++j) bfr[j] = *(const bf16x8*)&Bs[(nc + j * 16 + lm) * 32 + koff];
#pragma unroll
    for (int i = 0; i < 4; ++i)
#pragma unroll
      for (int j = 0; j < 4; ++j)
        acc[i][j] = __builtin_amdgcn_mfma_f32_16x16x32_bf16(af[i], bfr[j], acc[i][j], 0, 0, 0);
    __syncthreads();
  }

  if (MODE == 1) {  // RoPE -> [bh][s][d]
#pragma unroll
    for (int i = 0; i < 4; ++i) {
      const int mbase = m0 + mr + i * 16 + quad * 4;
#pragma unroll
      for (int j = 0; j < 4; ++j) {
        const int n = n0 + nc + j * 16 + lm;
        const int h = n >> 7, d = n & 127, ir = d >> 1;
#pragma unroll
        for (int r = 0; r < 4; ++r) {
          const int m = mbase + r;
          const int s = m & (S_ - 1);
          const int bb = m >> 11;
          float v = acc[i][j][r];
          float p = __shfl_xor(v, 1);
          float cv = fc[s * (HD_ / 2) + ir];
          float sv = fs[s * (HD_ / 2) + ir];
          float o = ((lane & 1) == 0) ? (v * cv - p * sv) : (p * sv + v * cv);
          float po = __shfl_xor(o, 1);
          if ((lane & 1) == 0) {
            unsigned pkt = rne_bf16(o) | (rne_bf16(po) << 16);
            size_t idx = (((size_t)(bb * H_ + h) * S_ + s) * HD_ + d) >> 1;
            ((unsigned*)outB)[idx] = pkt;
          }
        }
      }
    }
  } else if (MODE == 3) {  // V^T -> [bh][d][s]
#pragma unroll
    for (int i = 0; i < 4; ++i) {
      const int mbase = m0 + mr + i * 16 + quad * 4;
      const int s0 = mbase & (S_ - 1);
      const int bb = mbase >> 11;
#pragma unroll
      for (int j = 0; j < 4; ++j) {
        const int n = n0 + nc + j * 16 + lm;
        const int h = n >> 7, d = n & 127;
        uint2 pkt;
        pkt.x = rne_bf16(acc[i][j][0]) | (rne_bf16(acc[i][j][1]) << 16);
        pkt.y = rne_bf16(acc[i][j][2]) | (rne_bf16(acc[i][j][3]) << 16);
        size_t idx = ((size_t)(bb * H_ + h) * HD_ + d) * S_ + s0;
        *(uint2*)&outB[idx] = pkt;
      }
    }
  } else {  // fp32 out [m][n]
#pragma unroll
    for (int i = 0; i < 4; ++i) {
      const int mbase = m0 + mr + i * 16 + quad * 4;
#pragma unroll
      for (int j = 0; j < 4; ++j) {
        const int n = n0 + nc + j * 16 + lm;
#pragma unroll
        for (int r = 0; r < 4; ++r) outF[(size_t)(mbase + r) * D_ + n] = acc[i][j][r];
      }
    }
  }
}

// ---------------------------------------------------------------- flash attention v4
// S^T formulation, Q frags in registers, BQ=128, BK=64, T5 setprio, T13
// defer-max. THIS ROUND: LDS 64KB -> 48KB (K double-buffered as before;
// V SINGLE-buffered, staged at tile start and consumed after softmax behind
// VMW(4)+s_barrier). The mid-tile barrier provides cross-wave visibility of
// the cooperative V stage (each wave drains its own V ops via the counted
// VMW before arriving; vmcnt retires in order, so VMW(4) retires the 4 V
// chunks while leaving the 4 K-prefetch chunks in flight). 48KB + VGPR<=170
// (launch_bounds(256,3)) -> 3 blocks/CU (was 2): +50% resident waves.
// WAR audit: V-stage(kt) writes after top-of-kt __syncthreads, where
// PV(kt-1)'s ds_reads are lgkm-drained; K[nxt] stage pattern unchanged.
// Final tile: VMW(0) (only V's 4 ops outstanding). Waves that skip compute
// still execute VMW + barrier (outside the compute guard).
__global__ __launch_bounds__(256, 3) void flash_attn(
    const u16* __restrict__ Qb, const u16* __restrict__ Kb,
    const u16* __restrict__ Vtb, u16* __restrict__ attn) {
  // K buf p at p*8192 (16KB each), V buf at 16384 (16KB). 48 KB total.
  __shared__ __align__(16) u16 lds[24576];

  const int tid = threadIdx.x;
  const int lane = tid & 63, w = tid >> 6;
  const int lm = lane & 15, quad = lane >> 4;
  const int qb = 15 - blockIdx.x;  // heavy q-blocks first
  const int bh = blockIdx.y;
  const int bb = bh >> 5, h = bh & 31;

  const u16* Qg = Qb + ((size_t)bh * S_ + qb * 128 + w * 32) * HD_;
  const u16* Kg = Kb + (size_t)bh * S_ * HD_;
  const u16* Vg = Vtb + (size_t)bh * HD_ * S_;

  const u16* kp[4];
  const u16* vp[4];
#pragma unroll
  for (int it = 0; it < 4; ++it) {
    int c = tid + 256 * it;
    int kr = c >> 4, kc = (c & 15) ^ (kr & 15);
    kp[it] = Kg + (size_t)kr * HD_ + kc * 8;
    int vr = c >> 3, vc = (c & 7) ^ (vr & 7);
    vp[it] = Vg + (size_t)vr * S_ + vc * 8;
  }

  bf16x8 qf[2][4];
#pragma unroll
  for (int qt = 0; qt < 2; ++qt)
#pragma unroll
    for (int dk = 0; dk < 4; ++dk)
      qf[qt][dk] = *(const bf16x8*)(Qg + (size_t)(qt * 16 + lm) * HD_ + dk * 32 + quad * 8);

  f32x4 accO[8][2] = {};
  float m_run[2] = {-1e30f, -1e30f}, l_run[2] = {0.f, 0.f};
  const float scale = 0.08838834764831845f;  // 1/sqrt(128)
  const float THR = 90.50966799187809f;      // 8/scale
  const int nkt = 2 * qb + 2;
  const int qg0 = qb * 128 + w * 32;
  const int wq_max = qg0 + 31;

  // prologue: stage K(0) into K buf 0
#pragma unroll
  for (int it = 0; it < 4; ++it)
    async16(&lds[(tid + 256 * it) * 8], kp[it]);

  for (int kt = 0; kt < nkt; ++kt) {
    const int k0 = kt * 64;
    const int curK = (kt & 1) * 8192;
    __syncthreads();  // drains own vmcnt: K[cur] ready; V buf free (lgkm ok)
    {  // stage V(kt) (4 ops/thread), then prefetch K(kt+1) (4 ops/thread)
      const size_t koV = (size_t)kt * 64;
#pragma unroll
      for (int it = 0; it < 4; ++it)
        async16(&lds[16384 + (tid + 256 * it) * 8], vp[it] + koV);
      if (kt + 1 < nkt) {
        const size_t koK = (size_t)(kt + 1) * 64 * HD_;
#pragma unroll
        for (int it = 0; it < 4; ++it)
          async16(&lds[(curK ^ 8192) + (tid + 256 * it) * 8], kp[it] + koK);
      }
    }
    const bool live = (k0 <= wq_max);
    f32x4 sacc[2][4] = {};
    bf16x8 pf[2][2];  // P^T frags [kc][qt]
    if (live) {
      const u16* Ks = lds + curK;
#pragma unroll
      for (int dk = 0; dk < 4; ++dk) {
        bf16x8 kf[4];
#pragma unroll
        for (int t = 0; t < 4; ++t) {
          int row = (t >> 1) * 32 + ((lm >> 2) * 8) + ((t & 1) * 4) + (lm & 3);
          int ch = (dk * 4 + quad) ^ (row & 15);
          kf[t] = *(const bf16x8*)&Ks[(row * 16 + ch) * 8];
        }
        __builtin_amdgcn_s_setprio(1);
#pragma unroll
        for (int t = 0; t < 4; ++t)
#pragma unroll
          for (int qt = 0; qt < 2; ++qt)
            sacc[qt][t] = __builtin_amdgcn_mfma_f32_16x16x32_bf16(kf[t], qf[qt][dk], sacc[qt][t], 0, 0, 0);
        __builtin_amdgcn_s_setprio(0);
      }
      if (k0 + 63 > qg0) {  // causal mask on trailing tiles
#pragma unroll
        for (int qt = 0; qt < 2; ++qt) {
          int q = qg0 + qt * 16 + lm;
#pragma unroll
          for (int t = 0; t < 4; ++t) {
            int kb = k0 + (t >> 1) * 32 + quad * 8 + (t & 1) * 4;
#pragma unroll
            for (int r = 0; r < 4; ++r)
              if (kb + r > q) sacc[qt][t][r] = -1e30f;
          }
        }
      }
      // ---- online softmax with defer-max (T13)
      float tmaxv[2];
#pragma unroll
      for (int qt = 0; qt < 2; ++qt) {
        float tmax = sacc[qt][0][0];
#pragma unroll
        for (int t = 0; t < 4; ++t)
#pragma unroll
          for (int r = 0; r < 4; ++r) tmax = fmaxf(tmax, sacc[qt][t][r]);
        tmax = fmaxf(tmax, __shfl_xor(tmax, 16));
        tmax = fmaxf(tmax, __shfl_xor(tmax, 32));
        tmaxv[qt] = tmax;
      }
      bool needl = (tmaxv[0] - m_run[0] > THR) || (tmaxv[1] - m_run[1] > THR);
      if (__any(needl)) {
#pragma unroll
        for (int qt = 0; qt < 2; ++qt) {
          float mnew = fmaxf(m_run[qt], tmaxv[qt]);
          float alpha = __expf((m_run[qt] - mnew) * scale);
          m_run[qt] = mnew;
          l_run[qt] *= alpha;
#pragma unroll
          for (int dt = 0; dt < 8; ++dt)
#pragma unroll
            for (int r = 0; r < 4; ++r) accO[dt][qt][r] *= alpha;
        }
      }
#pragma unroll
      for (int qt = 0; qt < 2; ++qt) {
        float ms = m_run[qt] * scale;
        float rs = 0.f;
#pragma unroll
        for (int t = 0; t < 4; ++t)
#pragma unroll
          for (int r = 0; r < 4; ++r) {
            float p = __expf(fmaf(sacc[qt][t][r], scale, -ms));
            sacc[qt][t][r] = p;
            rs += p;
          }
        rs += __shfl_xor(rs, 16);
        rs += __shfl_xor(rs, 32);
        l_run[qt] += rs;
#pragma unroll
        for (int kc = 0; kc < 2; ++kc)
#pragma unroll
          for (int j = 0; j < 4; ++j) {
            pf[kc][qt][j]     = (__bf16)sacc[qt][2 * kc][j];
            pf[kc][qt][j + 4] = (__bf16)sacc[qt][2 * kc + 1][j];
          }
      }
    }
    // ---- V ready gate (ALL waves): own V ops drained, then barrier makes
    // every wave's staged chunks visible. In-order retire: with K(kt+1)
    // outstanding, VMW(4) retires exactly the (older) V ops.
    if (kt + 1 < nkt) {
      asm volatile("s_waitcnt vmcnt(4)" ::: "memory");
    } else {
      asm volatile("s_waitcnt vmcnt(0)" ::: "memory");
    }
    __builtin_amdgcn_s_barrier();
    if (live) {
      const u16* Vts = lds + 16384;
      __builtin_amdgcn_s_setprio(1);
#pragma unroll
      for (int kc = 0; kc < 2; ++kc)
#pragma unroll
        for (int dt = 0; dt < 8; ++dt) {
          int row = dt * 16 + lm;
          int ch = (kc * 4 + quad) ^ (row & 7);
          bf16x8 vf = *(const bf16x8*)&Vts[(row * 8 + ch) * 8];
#pragma unroll
          for (int qt = 0; qt < 2; ++qt)
            accO[dt][qt] = __builtin_amdgcn_mfma_f32_16x16x32_bf16(vf, pf[kc][qt], accO[dt][qt], 0, 0, 0);
        }
      __builtin_amdgcn_s_setprio(0);
    }
  }

  // ---- epilogue: transpose O^T -> O via LDS (reuse), coalesced store
  __syncthreads();
  u16* Et = lds;  // 128 q-rows x 136 u16 = 17408 u16 (fits in 24576)
  float inv[2] = {1.f / l_run[0], 1.f / l_run[1]};
#pragma unroll
  for (int dt = 0; dt < 8; ++dt)
#pragma unroll
    for (int qt = 0; qt < 2; ++qt) {
      const int rowq = w * 32 + qt * 16 + lm;
#pragma unroll
      for (int rp = 0; rp < 2; ++rp) {
        float a0 = accO[dt][qt][rp * 2] * inv[qt];
        float a1 = accO[dt][qt][rp * 2 + 1] * inv[qt];
        unsigned pkt = rne_bf16(a0) | (rne_bf16(a1) << 16);
        *(unsigned*)&Et[rowq * 136 + dt * 16 + quad * 4 + rp * 2] = pkt;
      }
    }
  const int rloc = w * 32 + (lane >> 1);
  const int half = lane & 1;
  const size_t gbase = (size_t)(bb * S_ + qb * 128 + rloc) * D_ + h * 128 + half * 64;
#pragma unroll
  for (int k = 0; k < 8; ++k) {
    uint4 vv = *(const uint4*)&Et[rloc * 136 + half * 64 + k * 8];
    *(uint4*)&attn[gbase + k * 8] = vv;
  }
}

// ---------------------------------------------------------------- launch
extern "C" void kernel_launch(void* const* d_in, const int* in_sizes, int n_in,
                              void* d_out, int out_size, void* d_ws, size_t ws_size,
                              hipStream_t stream) {
  const float* x  = (const float*)d_in[0];
  const float* fc = (const float*)d_in[1];
  const float* fs = (const float*)d_in[2];
  // d_in[3] = mask (causal, handled analytically)
  const float* wq = (const float*)d_in[4];
  const float* wk = (const float*)d_in[5];
  const float* wv = (const float*)d_in[6];
  const float* wo = (const float*)d_in[7];
  float* out = (float*)d_out;

  char* ws = (char*)d_ws;
  const size_t SZ = (size_t)B_ * S_ * D_ * 2;
  u16* xb  = (u16*)(ws);
  u16* wqb = (u16*)(ws + SZ);
  u16* wkb = (u16*)(ws + 2 * SZ);
  u16* wvb = (u16*)(ws + 3 * SZ);
  u16* Qb  = (u16*)(ws + 4 * SZ);
  u16* Kb  = (u16*)(ws + 5 * SZ);
  u16* Vtb = (u16*)(ws + 6 * SZ);
  u16* attn = xb;
  u16* wob  = wqb;

  dim3 blk(256);
  const int n8 = (B_ * S_ * D_) / 8;
  convert_bf16_x4<<<4 * (n8 / 256), blk, 0, stream>>>(x, wq, wk, wv, xb, wqb, wkb, wvb);

  dim3 g1(32, 32);
  gemm_bt<1><<<g1, blk, 0, stream>>>(xb, wqb, Qb, nullptr, fc, fs);
  gemm_bt<1><<<g1, blk, 0, stream>>>(xb, wkb, Kb, nullptr, fc, fs);
  gemm_bt<3><<<g1, blk, 0, stream>>>(xb, wvb, Vtb, nullptr, nullptr, nullptr);

  dim3 g2(16, 64);
  flash_attn<<<g2, blk, 0, stream>>>(Qb, Kb, Vtb, attn);

  convert_bf16<<<n8 / 256, blk, 0, stream>>>(wo, wob, n8);
  gemm_bt<4><<<g1, blk, 0, stream>>>(attn, wob, nullptr, out, nullptr, nullptr);
}